// Round 4
// baseline (1424.891 us; speedup 1.0000x reference)
//
#include <hip/hip_runtime.h>
#include <math.h>

#pragma clang fp contract(off)

#define RR 7
#define HH 2048
#define WW 2048
#define PH 2062
#define PW 2062
#define PITCH 2080
#define PLANE (PITCH * PH)

#define BLK 256
#define TX 242      // output columns per block (BLK - 14)
#define TYB 128     // output rows per block
#define NCHUNK 9    // ceil((TYB+16)/16) rows staged: y0-7 .. y0+136
#define GX 9        // ceil(2062/242)

__global__ __launch_bounds__(256) void sw_pad(const float* __restrict__ img,
                                              float* __restrict__ dst) {
    int idx = blockIdx.x * blockDim.x + threadIdx.x;
    if (idx >= PW * PH) return;
    int y = idx / PW, x = idx - y * PW;
    int sy = y - RR; sy = sy < 0 ? 0 : (sy > HH - 1 ? HH - 1 : sy);
    int sx = x - RR; sx = sx < 0 ? 0 : (sx > WW - 1 ? WW - 1 : sx);
    const float* p = img + ((long)sy * WW + sx) * 3;
    long o = (long)y * PITCH + x;
    dst[o] = p[0];
    dst[(long)PLANE + o] = p[1];
    dst[2L * PLANE + o] = p[2];
}

__global__ __launch_bounds__(256) void sw_crop(const float* __restrict__ src,
                                               float* __restrict__ out) {
    int idx = blockIdx.x * blockDim.x + threadIdx.x;
    if (idx >= HH * WW) return;
    int y = idx / WW, x = idx - y * WW;
    long o = (long)(y + RR) * PITCH + (x + RR);
    out[(long)idx * 3 + 0] = src[o];
    out[(long)idx * 3 + 1] = src[(long)PLANE + o];
    out[(long)idx * 3 + 2] = src[2L * PLANE + o];
}

// Horizontal stage sums: sequential ascending tap order, mul then add (no FMA).
__device__ __forceinline__ float hL8(const float* p) {
    float a = 0.125f * p[0];
    a = a + 0.125f * p[1];  a = a + 0.125f * p[2];
    a = a + 0.125f * p[3];  a = a + 0.125f * p[4];
    a = a + 0.125f * p[5];  a = a + 0.125f * p[6];
    a = a + 0.125f * p[7];
    return a;
}
__device__ __forceinline__ float hR8(const float* p) {
    float a = 0.125f * p[7];
    a = a + 0.125f * p[8];  a = a + 0.125f * p[9];
    a = a + 0.125f * p[10]; a = a + 0.125f * p[11];
    a = a + 0.125f * p[12]; a = a + 0.125f * p[13];
    a = a + 0.125f * p[14];
    return a;
}
__device__ __forceinline__ float hF15(const float* p) {
    const float c = 1.0f / 15.0f;
    float a = c * p[0];
    a = a + c * p[1];  a = a + c * p[2];  a = a + c * p[3];
    a = a + c * p[4];  a = a + c * p[5];  a = a + c * p[6];
    a = a + c * p[7];  a = a + c * p[8];  a = a + c * p[9];
    a = a + c * p[10]; a = a + c * p[11]; a = a + c * p[12];
    a = a + c * p[13]; a = a + c * p[14];
    return a;
}

__global__ __launch_bounds__(256, 2) void sw_iter(const float* __restrict__ src,
                                                  float* __restrict__ dst) {
    extern __shared__ float L[];           // 4 signals x 16 rows x 256 cols = 64 KB
    float* O1L = L;                        // vertical-Left conv output (f32, rounded)
    float* O1R = L + 16 * BLK;             // vertical-Right
    float* O1F = L + 32 * BLK;             // vertical-Full
    float* XC  = L + 48 * BLK;             // raw center row

    const int tid = threadIdx.x;
    const int x0 = blockIdx.x * TX;
    const int y0 = blockIdx.y * TYB;       // multiple of 16
    const int z = blockIdx.z;
    const float* sp = src + (long)z * PLANE;
    float* dp = dst + (long)z * PLANE;

    const int yend = min(y0 + TYB, PH);
    const int gcol = x0 - RR + tid;        // this thread's staged column
    const bool gok = (gcol >= 0) && (gcol < PW);
    const int ocol = x0 + tid;             // output column
    const bool comp = (tid < TX) && (ocol < PW);

    const float c15 = 1.0f / 15.0f;

    float xr[16];                          // ring: input rows t-15..t of column gcol
#pragma unroll
    for (int i = 0; i < 16; ++i) xr[i] = 0.0f;

    for (int c = 0; c < NCHUNK; ++c) {
        __syncthreads();                   // previous chunk's LDS fully consumed
#pragma unroll
        for (int s = 0; s < 16; ++s) {
            const int t = y0 - RR + 16 * c + s;     // new input row
            float v = 0.0f;
            if (gok && t >= 0 && t < PH) v = sp[(long)t * PITCH + gcol];
            xr[(s + 9) & 15] = v;                   // slot = t mod 16

            // vertical convs for center row m = t-7, sequential ascending taps,
            // each product rounded (no FMA), matching a naive f32 conv.
            // o1L: rows m-7..m  -> slots (s+11+k)&15, k=0..7
            float aL = 0.125f * xr[(s + 11) & 15];
            aL = aL + 0.125f * xr[(s + 12) & 15];
            aL = aL + 0.125f * xr[(s + 13) & 15];
            aL = aL + 0.125f * xr[(s + 14) & 15];
            aL = aL + 0.125f * xr[(s + 15) & 15];
            aL = aL + 0.125f * xr[(s + 16) & 15];
            aL = aL + 0.125f * xr[(s + 17) & 15];
            aL = aL + 0.125f * xr[(s + 18) & 15];
            // o1R: rows m..m+7 -> slots (s+2+k)&15, k=0..7
            float aR = 0.125f * xr[(s + 2) & 15];
            aR = aR + 0.125f * xr[(s + 3) & 15];
            aR = aR + 0.125f * xr[(s + 4) & 15];
            aR = aR + 0.125f * xr[(s + 5) & 15];
            aR = aR + 0.125f * xr[(s + 6) & 15];
            aR = aR + 0.125f * xr[(s + 7) & 15];
            aR = aR + 0.125f * xr[(s + 8) & 15];
            aR = aR + 0.125f * xr[(s + 9) & 15];
            // o1F: rows m-7..m+7 -> slots (s+11+k)&15, k=0..14
            float aF = c15 * xr[(s + 11) & 15];
            aF = aF + c15 * xr[(s + 12) & 15];
            aF = aF + c15 * xr[(s + 13) & 15];
            aF = aF + c15 * xr[(s + 14) & 15];
            aF = aF + c15 * xr[(s + 15) & 15];
            aF = aF + c15 * xr[(s + 16) & 15];
            aF = aF + c15 * xr[(s + 17) & 15];
            aF = aF + c15 * xr[(s + 18) & 15];
            aF = aF + c15 * xr[(s + 19) & 15];
            aF = aF + c15 * xr[(s + 20) & 15];
            aF = aF + c15 * xr[(s + 21) & 15];
            aF = aF + c15 * xr[(s + 22) & 15];
            aF = aF + c15 * xr[(s + 23) & 15];
            aF = aF + c15 * xr[(s + 24) & 15];
            aF = aF + c15 * xr[(s + 25) & 15];

            O1L[s * BLK + tid] = aL;
            O1R[s * BLK + tid] = aR;
            O1F[s * BLK + tid] = aF;
            XC[s * BLK + tid] = xr[(s + 2) & 15];   // raw x at row m = t-7
        }
        __syncthreads();
        if (comp) {
#pragma unroll
            for (int s = 0; s < 16; ++s) {
                const int tau = y0 + 16 * c + s - 14;   // output row (= center m)
                if (16 * c + s >= 14 && tau < yend) {
                    const float* pL = O1L + s * BLK + tid;
                    const float* pR = O1R + s * BLK + tid;
                    const float* pF = O1F + s * BLK + tid;
                    const float xc = XC[s * BLK + tid + 7];

                    float d0 = hL8(pL) - xc;    // (vL,hL)
                    float d1 = hR8(pL) - xc;    // (vL,hR)
                    float d2 = hL8(pR) - xc;    // (vR,hL)
                    float d3 = hR8(pR) - xc;    // (vR,hR)
                    float d4 = hF15(pL) - xc;   // (vL,hF)
                    float d5 = hF15(pR) - xc;   // (vR,hF)
                    float d6 = hL8(pF) - xc;    // (vF,hL)
                    float d7 = hR8(pF) - xc;    // (vF,hR)

                    float best = d0, ba = fabsf(d0), a;
                    a = fabsf(d1); if (a < ba) { ba = a; best = d1; }
                    a = fabsf(d2); if (a < ba) { ba = a; best = d2; }
                    a = fabsf(d3); if (a < ba) { ba = a; best = d3; }
                    a = fabsf(d4); if (a < ba) { ba = a; best = d4; }
                    a = fabsf(d5); if (a < ba) { ba = a; best = d5; }
                    a = fabsf(d6); if (a < ba) { ba = a; best = d6; }
                    a = fabsf(d7); if (a < ba) { ba = a; best = d7; }

                    dp[(long)tau * PITCH + ocol] = xc + best;
                }
            }
        }
    }
}

extern "C" void kernel_launch(void* const* d_in, const int* in_sizes, int n_in,
                              void* d_out, int out_size, void* d_ws, size_t ws_size,
                              hipStream_t stream) {
    (void)in_sizes; (void)n_in; (void)out_size; (void)ws_size;
    const float* img = (const float*)d_in[0];
    float* out = (float*)d_out;
    float* A = (float*)d_ws;
    float* B = A + 3L * PLANE;

    {
        int total = PW * PH;
        int g = (total + 255) / 256;
        sw_pad<<<dim3(g), dim3(256), 0, stream>>>(img, A);
    }
    dim3 grid(GX, 17, 3), block(BLK);
    for (int i = 0; i < 10; ++i) {
        const float* s = (i & 1) ? B : A;
        float* d = (i & 1) ? A : B;
        sw_iter<<<grid, block, 64 * BLK * sizeof(float), stream>>>(s, d);
    }
    // iter 9 (odd) writes A: final state in A.
    {
        int total = HH * WW;
        int g = (total + 255) / 256;
        sw_crop<<<dim3(g), dim3(256), 0, stream>>>(A, out);
    }
}